// Round 1
// baseline (8212.218 us; speedup 1.0000x reference)
//
#include <hip/hip_runtime.h>
#include <cstdint>
#include <cstddef>

typedef uint16_t u16;
typedef __attribute__((ext_vector_type(8))) __bf16 bf16x8;
typedef __attribute__((ext_vector_type(4))) float f32x4;

#define DEVI static __device__ __forceinline__

DEVI u16 f2bf(float f) {
    union { float f; uint32_t u; } x; x.f = f;
    uint32_t r = (x.u + 0x7fffu + ((x.u >> 16) & 1u)) >> 16;
    return (u16)r;
}

DEVI void async_load16(const u16* g, const u16* l) {
    __builtin_amdgcn_global_load_lds(
        (__attribute__((address_space(1))) uint32_t*)(uintptr_t)g,
        (__attribute__((address_space(3))) uint32_t*)(uintptr_t)l,
        16, 0, 0);
}

enum { EP_QKV = 0, EP_RESID = 1, EP_GELU = 2, EP_COND = 3 };

// C = A(bf16 MxK) @ Bt(bf16 NxK)^T + bias, various epilogues.
// 128x128 tile, BK=32, 256 threads, 2x2 waves of 4x4 16x16x32 mfma.
template<int EP>
__global__ __launch_bounds__(256)
void gemm_k(const u16* __restrict__ A, const u16* __restrict__ Bt,
            int M, int N, int K,
            const float* __restrict__ bias0, const float* __restrict__ bias1,
            const float* __restrict__ bias2,
            float* __restrict__ xout, u16* __restrict__ bfout,
            const float* __restrict__ pos)
{
    __shared__ u16 As[128 * 32];
    __shared__ u16 Bs[128 * 32];
    const int tid = threadIdx.x;
    const int m0 = blockIdx.y * 128;
    const int n0 = blockIdx.x * 128;
    const int lane = tid & 63;
    const int wave = tid >> 6;
    const int quad = lane >> 4;
    const int l16 = lane & 15;
    const int wr = (wave >> 1) * 64;
    const int wc = (wave & 1) * 64;

    f32x4 acc[4][4] = {};

    const int srow = tid >> 2;   // 0..63
    const int sseg = tid & 3;    // 0..3
    const u16* aptr = A + (size_t)(m0 + srow) * K + sseg * 8;
    const u16* bptr = Bt + (size_t)(n0 + srow) * K + sseg * 8;

    for (int kb = 0; kb < K; kb += 32) {
        __syncthreads();
        async_load16(aptr + kb, As + tid * 8);
        async_load16(aptr + (size_t)64 * K + kb, As + 2048 + tid * 8);
        async_load16(bptr + kb, Bs + tid * 8);
        async_load16(bptr + (size_t)64 * K + kb, Bs + 2048 + tid * 8);
        __syncthreads();
        bf16x8 af[4], bfr[4];
        #pragma unroll
        for (int i = 0; i < 4; i++)
            af[i] = *(const bf16x8*)(As + (wr + i * 16 + l16) * 32 + quad * 8);
        #pragma unroll
        for (int i = 0; i < 4; i++)
            bfr[i] = *(const bf16x8*)(Bs + (wc + i * 16 + l16) * 32 + quad * 8);
        #pragma unroll
        for (int mi = 0; mi < 4; mi++)
            #pragma unroll
            for (int ni = 0; ni < 4; ni++)
                acc[mi][ni] = __builtin_amdgcn_mfma_f32_16x16x32_bf16(
                    af[mi], bfr[ni], acc[mi][ni], 0, 0, 0);
    }

    #pragma unroll
    for (int mi = 0; mi < 4; mi++) {
        const int rbase = m0 + wr + mi * 16 + quad * 4;
        #pragma unroll
        for (int ni = 0; ni < 4; ni++) {
            const int col = n0 + wc + ni * 16 + l16;
            float bias;
            if (EP == EP_QKV)
                bias = (col < 768) ? bias0[col]
                     : (col < 1536) ? bias1[col - 768] : bias2[col - 1536];
            else
                bias = bias0[col];
            #pragma unroll
            for (int r = 0; r < 4; r++) {
                const int row = rbase + r;
                float v = acc[mi][ni][r] + bias;
                if (EP == EP_QKV) {
                    bfout[(size_t)row * N + col] = f2bf(v);
                } else if (EP == EP_GELU) {
                    v = 0.5f * v * (1.0f + erff(v * 0.70710678f));
                    bfout[(size_t)row * N + col] = f2bf(v);
                } else if (EP == EP_RESID) {
                    xout[(size_t)row * N + col] += v;
                } else { // EP_COND: row in [0,4096) -> x[b*1536 + i], + pos
                    const int b = row >> 9, i = row & 511;
                    xout[((size_t)(b * 1536 + i)) * 768 + col] =
                        v + pos[(size_t)i * 768 + col];
                }
            }
        }
    }
}

// LayerNorm: one wave per row of 768, write bf16.
__global__ __launch_bounds__(256)
void ln_k(const float* __restrict__ x, const float* __restrict__ w,
          const float* __restrict__ b, u16* __restrict__ h)
{
    const int row = blockIdx.x * 4 + (threadIdx.x >> 6);
    const int lane = threadIdx.x & 63;
    const float* xr = x + (size_t)row * 768;
    float vals[12];
    float s = 0.f;
    #pragma unroll
    for (int i = 0; i < 12; i++) { vals[i] = xr[lane + i * 64]; s += vals[i]; }
    #pragma unroll
    for (int o = 32; o; o >>= 1) s += __shfl_xor(s, o);
    const float mean = s * (1.f / 768.f);
    float vs = 0.f;
    #pragma unroll
    for (int i = 0; i < 12; i++) { float d = vals[i] - mean; vs += d * d; }
    #pragma unroll
    for (int o = 32; o; o >>= 1) vs += __shfl_xor(vs, o);
    const float rstd = rsqrtf(vs * (1.f / 768.f) + 1e-5f);
    u16* hr = h + (size_t)row * 768;
    #pragma unroll
    for (int i = 0; i < 12; i++) {
        const int c = lane + i * 64;
        hr[c] = f2bf((vals[i] - mean) * rstd * w[c] + b[c]);
    }
}

// Flash attention. qkv: [12288][2304] bf16 (q|k|v per head inside).
// Block: (qt, h, b), 4 waves, each wave 16 q-rows. Key blocks of 32.
__global__ __launch_bounds__(256)
void attn_k(const u16* __restrict__ qkv, u16* __restrict__ y)
{
    __shared__ u16 Vt[64 * 40];     // [hd][key], stride 40
    __shared__ u16 P[4][16 * 40];   // per-wave, [qrow][key], stride 40
    const int qt = blockIdx.x, hh = blockIdx.y, b = blockIdx.z;
    const int tid = threadIdx.x, wave = tid >> 6, lane = tid & 63;
    const int quad = lane >> 4, l16 = lane & 15;
    const size_t RS = 2304;
    const u16* qb = qkv + (size_t)b * 1536 * RS + hh * 64;
    const u16* kbp = qb + 768;
    const u16* vbp = qb + 1536;
    const int q0 = qt * 64 + wave * 16;
    const int li0 = q0 & 511;
    const int li_max = ((qt * 64) & 511) + 63;

    bf16x8 qf[2];
    #pragma unroll
    for (int st = 0; st < 2; st++)
        qf[st] = *(const bf16x8*)(qb + (size_t)(q0 + l16) * RS + st * 32 + quad * 8);

    f32x4 o_acc[4] = {};
    float m_i[4], l_i[4];
    #pragma unroll
    for (int r = 0; r < 4; r++) { m_i[r] = -1e30f; l_i[r] = 0.f; }
    const float scale = 0.125f;
    const int vkey = tid & 31, vhc = tid >> 5;

    for (int kt = 0; kt < 48; kt++) {
        const int kl = (kt * 32) & 511;
        if (kl > li_max) continue;           // block-uniform skip
        __syncthreads();
        {   // stage V^T: thread loads 8 hd of one key, scatters to [hd][key]
            bf16x8 vv = *(const bf16x8*)(vbp + (size_t)(kt * 32 + vkey) * RS + vhc * 8);
            const u16* vr = (const u16*)&vv;
            #pragma unroll
            for (int j = 0; j < 8; j++) Vt[(vhc * 8 + j) * 40 + vkey] = vr[j];
        }
        __syncthreads();

        f32x4 sf[2] = {};
        #pragma unroll
        for (int g = 0; g < 2; g++)
            #pragma unroll
            for (int st = 0; st < 2; st++) {
                bf16x8 kf = *(const bf16x8*)(kbp +
                    (size_t)(kt * 32 + g * 16 + l16) * RS + st * 32 + quad * 8);
                sf[g] = __builtin_amdgcn_mfma_f32_16x16x32_bf16(qf[st], kf, sf[g], 0, 0, 0);
            }

        const bool need_mask = (kl + 31 > li0);
        #pragma unroll
        for (int r = 0; r < 4; r++) {
            float v0 = sf[0][r] * scale, v1 = sf[1][r] * scale;
            if (need_mask) {
                const int li = li0 + quad * 4 + r;
                if (kl + l16 > li) v0 = -1e30f;
                if (kl + 16 + l16 > li) v1 = -1e30f;
            }
            float mx = fmaxf(v0, v1);
            #pragma unroll
            for (int o = 8; o; o >>= 1) mx = fmaxf(mx, __shfl_xor(mx, o));
            const float mnew = fmaxf(m_i[r], mx);
            const float alpha = __expf(m_i[r] - mnew);
            v0 = __expf(v0 - mnew); v1 = __expf(v1 - mnew);
            float ps = v0 + v1;
            #pragma unroll
            for (int o = 8; o; o >>= 1) ps += __shfl_xor(ps, o);
            l_i[r] = l_i[r] * alpha + ps;
            m_i[r] = mnew;
            P[wave][(quad * 4 + r) * 40 + l16] = f2bf(v0);
            P[wave][(quad * 4 + r) * 40 + 16 + l16] = f2bf(v1);
            #pragma unroll
            for (int n = 0; n < 4; n++) o_acc[n][r] *= alpha;
        }
        __syncthreads();
        bf16x8 pf = *(const bf16x8*)(&P[wave][l16 * 40 + quad * 8]);
        #pragma unroll
        for (int n = 0; n < 4; n++) {
            bf16x8 vf = *(const bf16x8*)(&Vt[(n * 16 + l16) * 40 + quad * 8]);
            o_acc[n] = __builtin_amdgcn_mfma_f32_16x16x32_bf16(pf, vf, o_acc[n], 0, 0, 0);
        }
    }
    #pragma unroll
    for (int r = 0; r < 4; r++) {
        const float inv = 1.f / l_i[r];
        const size_t row = (size_t)b * 1536 + qt * 64 + wave * 16 + quad * 4 + r;
        #pragma unroll
        for (int n = 0; n < 4; n++)
            y[row * 768 + hh * 64 + n * 16 + l16] = f2bf(o_acc[n][r] * inv);
    }
}

// Transpose+convert one layer's 6 weight mats: fp32 KxN -> bf16 NxK.
__global__ __launch_bounds__(256)
void cvt_layer_k(const float* __restrict__ Wq, const float* __restrict__ Wk,
                 const float* __restrict__ Wv, const float* __restrict__ Wp,
                 const float* __restrict__ W1, const float* __restrict__ W2,
                 u16* __restrict__ Wt)
{
    int id = blockIdx.x;
    const float* src; u16* dst; int Kd, Nd;
    if (id < 2304) {
        const int m = id / 576; id -= m * 576;
        src = (m == 0) ? Wq : (m == 1) ? Wk : (m == 2) ? Wv : Wp;
        dst = Wt + (size_t)m * 589824; Kd = 768; Nd = 768;
    } else if (id < 4608) {
        id -= 2304; src = W1; dst = Wt + (size_t)4 * 589824; Kd = 768; Nd = 3072;
    } else {
        id -= 4608; src = W2; dst = Wt + (size_t)4 * 589824 + 2359296; Kd = 3072; Nd = 768;
    }
    const int tn_n = Nd >> 5;
    const int tk = id / tn_n, tn = id - tk * tn_n;
    __shared__ float tile[32][33];
    const int tx = threadIdx.x & 31, ty = threadIdx.x >> 5;
    #pragma unroll
    for (int i = 0; i < 4; i++)
        tile[ty + i * 8][tx] = src[(size_t)(tk * 32 + ty + i * 8) * Nd + tn * 32 + tx];
    __syncthreads();
    #pragma unroll
    for (int i = 0; i < 4; i++)
        dst[(size_t)(tn * 32 + ty + i * 8) * Kd + tk * 32 + tx] = f2bf(tile[tx][ty + i * 8]);
}

__global__ void cvt_cond_k(const float* __restrict__ cond, u16* __restrict__ condb) {
    const int r = blockIdx.x, k = threadIdx.x;
    condb[(size_t)r * 448 + k] = (k < 438) ? f2bf(cond[(size_t)r * 438 + k]) : (u16)0;
}
__global__ void cvt_condw_k(const float* __restrict__ cw, u16* __restrict__ cwt) {
    const int n = blockIdx.x, k = threadIdx.x;
    cwt[(size_t)n * 448 + k] = (k < 438) ? f2bf(cw[(size_t)k * 768 + n]) : (u16)0;
}

// Token + positional embedding for segments 1,2 (rows 512..1535 per b).
__global__ void embed_k(const int* __restrict__ iu, const int* __restrict__ idn,
                        const float* __restrict__ eu, const float* __restrict__ ed,
                        const float* __restrict__ pos, float* __restrict__ x)
{
    const int t = blockIdx.x * 256 + threadIdx.x;  // 8*1024*192 float4s
    const int d4 = t % 192;
    const int row = t / 192;
    const int b = row >> 10, pl = row & 1023;
    const float* src; int posrow;
    if (pl < 512) { src = eu + (size_t)iu[b * 512 + pl] * 768; posrow = 512 + pl; }
    else { src = ed + (size_t)idn[b * 512 + pl - 512] * 768; posrow = 1024 + (pl - 512); }
    float4 v = ((const float4*)src)[d4];
    const float4 p = ((const float4*)(pos + (size_t)posrow * 768))[d4];
    v.x += p.x; v.y += p.y; v.z += p.z; v.w += p.w;
    ((float4*)(x + ((size_t)b * 1536 + posrow) * 768))[d4] = v;
}

extern "C" void kernel_launch(void* const* d_in, const int* in_sizes, int n_in,
                              void* d_out, int out_size, void* d_ws, size_t ws_size,
                              hipStream_t stream)
{
    const int*   idx_up   = (const int*)d_in[0];
    const int*   idx_down = (const int*)d_in[1];
    const float* cond     = (const float*)d_in[2];
    const float* emb_up   = (const float*)d_in[3];
    const float* emb_down = (const float*)d_in[4];
    const float* pos      = (const float*)d_in[5];
    const float* cond_w   = (const float*)d_in[6];
    const float* cond_b   = (const float*)d_in[7];
    const float* ln1_w    = (const float*)d_in[8];
    const float* ln1_b    = (const float*)d_in[9];
    const float* ln2_w    = (const float*)d_in[10];
    const float* ln2_b    = (const float*)d_in[11];
    const float* Wq = (const float*)d_in[12]; const float* bq = (const float*)d_in[13];
    const float* Wk = (const float*)d_in[14]; const float* bk = (const float*)d_in[15];
    const float* Wv = (const float*)d_in[16]; const float* bv = (const float*)d_in[17];
    const float* Wp = (const float*)d_in[18]; const float* bp = (const float*)d_in[19];
    const float* W1 = (const float*)d_in[20]; const float* b1 = (const float*)d_in[21];
    const float* W2 = (const float*)d_in[22]; const float* b2 = (const float*)d_in[23];

    float* x = (float*)d_out;  // residual stream lives in d_out (B,T,D) fp32

    u16* h     = (u16*)d_ws;           // 12288x768
    u16* qkv   = h + 9437184;          // 12288x2304
    u16* y     = qkv + 28311552;       // 12288x768
    u16* h1    = y + 9437184;          // 12288x3072
    u16* Wt    = h1 + 37748736;        // 7077888 (per-layer slot)
    u16* condb = Wt + 7077888;         // 4096x448
    u16* cwt   = condb + 1835008;      // 768x448

    cvt_cond_k<<<4096, 448, 0, stream>>>(cond, condb);
    cvt_condw_k<<<768, 448, 0, stream>>>(cond_w, cwt);
    embed_k<<<6144, 256, 0, stream>>>(idx_up, idx_down, emb_up, emb_down, pos, x);
    gemm_k<EP_COND><<<dim3(6, 32), 256, 0, stream>>>(condb, cwt, 4096, 768, 448,
        cond_b, nullptr, nullptr, x, nullptr, pos);

    for (int l = 0; l < 12; l++) {
        cvt_layer_k<<<6912, 256, 0, stream>>>(
            Wq + (size_t)l * 589824, Wk + (size_t)l * 589824, Wv + (size_t)l * 589824,
            Wp + (size_t)l * 589824, W1 + (size_t)l * 2359296, W2 + (size_t)l * 2359296, Wt);
        ln_k<<<3072, 256, 0, stream>>>(x, ln1_w + l * 768, ln1_b + l * 768, h);
        gemm_k<EP_QKV><<<dim3(18, 96), 256, 0, stream>>>(h, Wt, 12288, 2304, 768,
            bq + l * 768, bk + l * 768, bv + l * 768, nullptr, qkv, nullptr);
        attn_k<<<dim3(24, 12, 8), 256, 0, stream>>>(qkv, y);
        gemm_k<EP_RESID><<<dim3(6, 96), 256, 0, stream>>>(y, Wt + (size_t)3 * 589824,
            12288, 768, 768, bp + l * 768, nullptr, nullptr, x, nullptr, nullptr);
        ln_k<<<3072, 256, 0, stream>>>(x, ln2_w + l * 768, ln2_b + l * 768, h);
        gemm_k<EP_GELU><<<dim3(24, 96), 256, 0, stream>>>(h, Wt + (size_t)4 * 589824,
            12288, 3072, 768, b1 + l * 3072, nullptr, nullptr, nullptr, h1, nullptr);
        gemm_k<EP_RESID><<<dim3(6, 96), 256, 0, stream>>>(h1,
            Wt + (size_t)4 * 589824 + 2359296, 12288, 768, 3072,
            b2 + l * 768, nullptr, nullptr, x, nullptr, nullptr);
    }
}

// Round 2
// 6463.304 us; speedup vs baseline: 1.2706x; 1.2706x over previous
//
#include <hip/hip_runtime.h>
#include <cstdint>
#include <cstddef>

typedef uint16_t u16;
typedef __attribute__((ext_vector_type(8))) __bf16 bf16x8;
typedef __attribute__((ext_vector_type(4))) float f32x4;

#define DEVI static __device__ __forceinline__

DEVI u16 f2bf(float f) {
    union { float f; uint32_t u; } x; x.f = f;
    uint32_t r = (x.u + 0x7fffu + ((x.u >> 16) & 1u)) >> 16;
    return (u16)r;
}

DEVI void async_load16(const u16* g, const u16* l) {
    __builtin_amdgcn_global_load_lds(
        (__attribute__((address_space(1))) uint32_t*)(uintptr_t)g,
        (__attribute__((address_space(3))) uint32_t*)(uintptr_t)l,
        16, 0, 0);
}

enum { EP_QKV = 0, EP_RESID = 1, EP_GELU = 2, EP_COND = 3 };

// C = A(bf16 MxK) @ Bt(bf16 NxK)^T + bias, various epilogues.
// 128x128 tile, BK=32, 256 threads, 2x2 waves of 4x4 16x16x32 mfma.
template<int EP>
__global__ __launch_bounds__(256)
void gemm_k(const u16* __restrict__ A, const u16* __restrict__ Bt,
            int M, int N, int K,
            const float* __restrict__ bias0, const float* __restrict__ bias1,
            const float* __restrict__ bias2,
            float* __restrict__ xout, u16* __restrict__ bfout,
            const float* __restrict__ pos)
{
    __shared__ u16 As[128 * 32];
    __shared__ u16 Bs[128 * 32];
    const int tid = threadIdx.x;
    const int m0 = blockIdx.y * 128;
    const int n0 = blockIdx.x * 128;
    const int lane = tid & 63;
    const int wave = tid >> 6;
    const int quad = lane >> 4;
    const int l16 = lane & 15;
    const int wr = (wave >> 1) * 64;
    const int wc = (wave & 1) * 64;

    f32x4 acc[4][4] = {};

    const int srow = tid >> 2;   // 0..63
    const int sseg = tid & 3;    // 0..3
    const u16* aptr = A + (size_t)(m0 + srow) * K + sseg * 8;
    const u16* bptr = Bt + (size_t)(n0 + srow) * K + sseg * 8;

    for (int kb = 0; kb < K; kb += 32) {
        __syncthreads();
        async_load16(aptr + kb, As + tid * 8);
        async_load16(aptr + (size_t)64 * K + kb, As + 2048 + tid * 8);
        async_load16(bptr + kb, Bs + tid * 8);
        async_load16(bptr + (size_t)64 * K + kb, Bs + 2048 + tid * 8);
        __syncthreads();
        bf16x8 af[4], bfr[4];
        #pragma unroll
        for (int i = 0; i < 4; i++)
            af[i] = *(const bf16x8*)(As + (wr + i * 16 + l16) * 32 + quad * 8);
        #pragma unroll
        for (int i = 0; i < 4; i++)
            bfr[i] = *(const bf16x8*)(Bs + (wc + i * 16 + l16) * 32 + quad * 8);
        #pragma unroll
        for (int mi = 0; mi < 4; mi++)
            #pragma unroll
            for (int ni = 0; ni < 4; ni++)
                acc[mi][ni] = __builtin_amdgcn_mfma_f32_16x16x32_bf16(
                    af[mi], bfr[ni], acc[mi][ni], 0, 0, 0);
    }

    #pragma unroll
    for (int mi = 0; mi < 4; mi++) {
        const int rbase = m0 + wr + mi * 16 + quad * 4;
        #pragma unroll
        for (int ni = 0; ni < 4; ni++) {
            const int col = n0 + wc + ni * 16 + l16;
            float bias;
            if (EP == EP_QKV)
                bias = (col < 768) ? bias0[col]
                     : (col < 1536) ? bias1[col - 768] : bias2[col - 1536];
            else
                bias = bias0[col];
            #pragma unroll
            for (int r = 0; r < 4; r++) {
                const int row = rbase + r;
                float v = acc[mi][ni][r] + bias;
                if (EP == EP_QKV) {
                    bfout[(size_t)row * N + col] = f2bf(v);
                } else if (EP == EP_GELU) {
                    v = 0.5f * v * (1.0f + erff(v * 0.70710678f));
                    bfout[(size_t)row * N + col] = f2bf(v);
                } else if (EP == EP_RESID) {
                    xout[(size_t)row * N + col] += v;
                } else { // EP_COND: row in [0,4096) -> x[b*1536 + i], + pos
                    const int b = row >> 9, i = row & 511;
                    xout[((size_t)(b * 1536 + i)) * 768 + col] =
                        v + pos[(size_t)i * 768 + col];
                }
            }
        }
    }
}

// LayerNorm: one wave per row of 768, write bf16.
__global__ __launch_bounds__(256)
void ln_k(const float* __restrict__ x, const float* __restrict__ w,
          const float* __restrict__ b, u16* __restrict__ h)
{
    const int row = blockIdx.x * 4 + (threadIdx.x >> 6);
    const int lane = threadIdx.x & 63;
    const float* xr = x + (size_t)row * 768;
    float vals[12];
    float s = 0.f;
    #pragma unroll
    for (int i = 0; i < 12; i++) { vals[i] = xr[lane + i * 64]; s += vals[i]; }
    #pragma unroll
    for (int o = 32; o; o >>= 1) s += __shfl_xor(s, o);
    const float mean = s * (1.f / 768.f);
    float vs = 0.f;
    #pragma unroll
    for (int i = 0; i < 12; i++) { float d = vals[i] - mean; vs += d * d; }
    #pragma unroll
    for (int o = 32; o; o >>= 1) vs += __shfl_xor(vs, o);
    const float rstd = rsqrtf(vs * (1.f / 768.f) + 1e-5f);
    u16* hr = h + (size_t)row * 768;
    #pragma unroll
    for (int i = 0; i < 12; i++) {
        const int c = lane + i * 64;
        hr[c] = f2bf((vals[i] - mean) * rstd * w[c] + b[c]);
    }
}

// Flash attention, S^T scheme: S^T = K Q^T so q lives in lane index and the
// softmax reduction over keys is in-register (+2 shuffles), m/l state lane-local.
// Block: (qt, h, b), 4 waves x 16 q-rows; 64-key tiles; K,V staged in LDS once.
__global__ __launch_bounds__(256)
void attn_k(const u16* __restrict__ qkv, u16* __restrict__ y)
{
    __shared__ u16 Ks[64 * 64];      // [key][hd], 16B chunks XOR-swizzled
    __shared__ u16 Vt[64 * 64];      // [hd][key], 16B chunks XOR-swizzled
    __shared__ u16 Ps[4][16 * 72];   // per-wave P[q][key], stride 72 (16B aligned)
    const int qt = blockIdx.x, hh = blockIdx.y, b = blockIdx.z;
    const int tid = threadIdx.x, wave = tid >> 6, lane = tid & 63;
    const int quad = lane >> 4, l16 = lane & 15;
    const int l7 = l16 & 7;
    const size_t RS = 2304;
    const u16* qb  = qkv + (size_t)b * 1536 * RS + hh * 64;
    const u16* kbp = qb + 768;
    const u16* vbp = qb + 1536;

    // Q fragment (B-operand): n = q = l16, k = st*32 + quad*8 + j
    bf16x8 qf[2];
    {
        const u16* qr = qb + (size_t)(qt * 64 + wave * 16 + l16) * RS + quad * 8;
        qf[0] = *(const bf16x8*)(qr);
        qf[1] = *(const bf16x8*)(qr + 32);
    }

    f32x4 o_acc[4] = {};
    float m_i = -1e30f, l_i = 0.f;
    const float scale = 0.125f;

    const int srow = tid >> 2;   // K staging: key row 0..63
    const int sseg = tid & 3;    // chunk 0..3 (and +4)
    const int vkey = tid & 63, vw = tid >> 6;
    const int kmax = qt & 7;

    for (int seg3 = 0; seg3 < 3; seg3++) {
        for (int k8 = 0; k8 <= kmax; k8++) {
            const int kt = seg3 * 8 + k8;
            const bool diag = (k8 == kmax);
            __syncthreads();
            {   // stage K: 2 coalesced 16B loads -> swizzled 16B LDS writes
                const u16* krow = kbp + (size_t)(kt * 64 + srow) * RS;
                bf16x8 c0 = *(const bf16x8*)(krow + sseg * 8);
                bf16x8 c1 = *(const bf16x8*)(krow + (sseg + 4) * 8);
                const int sw = srow & 7;
                *(bf16x8*)(Ks + srow * 64 + ((sseg    ) ^ sw) * 8) = c0;
                *(bf16x8*)(Ks + srow * 64 + ((sseg + 4) ^ sw) * 8) = c1;
            }
            {   // stage V^T: scatter, conflict-free scalar writes
                const u16* vrow = vbp + (size_t)(kt * 64 + vkey) * RS;
                const int kc = vkey >> 3, ko = vkey & 7;
                #pragma unroll
                for (int i = 0; i < 2; i++) {
                    bf16x8 vv = *(const bf16x8*)(vrow + (vw + i * 4) * 8);
                    const u16* vr = (const u16*)&vv;
                    #pragma unroll
                    for (int j = 0; j < 8; j++) {
                        const int hd = (vw + i * 4) * 8 + j;
                        Vt[hd * 64 + ((kc ^ j) * 8) + ko] = vr[j];
                    }
                }
            }
            __syncthreads();

            // S^T = K Q^T : 4 accs of [16key x 16q]; row=key(quad*4+r), col=q(l16)
            f32x4 sacc[4] = {};
            #pragma unroll
            for (int st = 0; st < 2; st++)
                #pragma unroll
                for (int kb = 0; kb < 4; kb++) {
                    bf16x8 kf = *(const bf16x8*)(Ks + (kb * 16 + l16) * 64 +
                                    ((st * 4 + quad) ^ l7) * 8);
                    sacc[kb] = __builtin_amdgcn_mfma_f32_16x16x32_bf16(
                        kf, qf[st], sacc[kb], 0, 0, 0);
                }

            // online softmax, per-lane q = l16 (replicated over quads)
            float sv[16];
            const int thr = wave * 16 + l16;
            #pragma unroll
            for (int kb = 0; kb < 4; kb++)
                #pragma unroll
                for (int r = 0; r < 4; r++) {
                    float v = sacc[kb][r] * scale;
                    if (diag && (kb * 16 + quad * 4 + r > thr)) v = -1e30f;
                    sv[kb * 4 + r] = v;
                }
            float mx = sv[0];
            #pragma unroll
            for (int i = 1; i < 16; i++) mx = fmaxf(mx, sv[i]);
            mx = fmaxf(mx, __shfl_xor(mx, 16));
            mx = fmaxf(mx, __shfl_xor(mx, 32));
            const float mnew = fmaxf(m_i, mx);
            const float alpha = __expf(m_i - mnew);
            float ps = 0.f;
            #pragma unroll
            for (int i = 0; i < 16; i++) { sv[i] = __expf(sv[i] - mnew); ps += sv[i]; }
            ps += __shfl_xor(ps, 16);
            ps += __shfl_xor(ps, 32);
            l_i = l_i * alpha + ps;
            m_i = mnew;
            #pragma unroll
            for (int n = 0; n < 4; n++) {
                o_acc[n][0] *= alpha; o_acc[n][1] *= alpha;
                o_acc[n][2] *= alpha; o_acc[n][3] *= alpha;
            }
            // pack P[q=l16][key]: 4x 8B writes
            #pragma unroll
            for (int kb = 0; kb < 4; kb++) {
                ushort4 p4;
                p4.x = f2bf(sv[kb * 4 + 0]); p4.y = f2bf(sv[kb * 4 + 1]);
                p4.z = f2bf(sv[kb * 4 + 2]); p4.w = f2bf(sv[kb * 4 + 3]);
                *(ushort4*)(&Ps[wave][l16 * 72 + kb * 16 + quad * 4]) = p4;
            }
            // O^T += V^T P^T : A=vf (hd rows), B=pf (q cols); within-wave LDS RAW
            #pragma unroll
            for (int st = 0; st < 2; st++) {
                bf16x8 pf = *(const bf16x8*)(&Ps[wave][l16 * 72 + st * 32 + quad * 8]);
                #pragma unroll
                for (int n = 0; n < 4; n++) {
                    bf16x8 vf = *(const bf16x8*)(Vt + (n * 16 + l16) * 64 +
                                    ((st * 4 + quad) ^ l7) * 8);
                    o_acc[n] = __builtin_amdgcn_mfma_f32_16x16x32_bf16(
                        vf, pf, o_acc[n], 0, 0, 0);
                }
            }
        }
    }

    const float inv = 1.f / l_i;
    u16* yr = y + ((size_t)b * 1536 + qt * 64 + wave * 16 + l16) * 768 + hh * 64;
    #pragma unroll
    for (int n = 0; n < 4; n++) {
        ushort4 o4;
        o4.x = f2bf(o_acc[n][0] * inv);
        o4.y = f2bf(o_acc[n][1] * inv);
        o4.z = f2bf(o_acc[n][2] * inv);
        o4.w = f2bf(o_acc[n][3] * inv);
        *(ushort4*)(yr + n * 16 + quad * 4) = o4;
    }
}

// Transpose+convert one layer's 6 weight mats: fp32 KxN -> bf16 NxK.
__global__ __launch_bounds__(256)
void cvt_layer_k(const float* __restrict__ Wq, const float* __restrict__ Wk,
                 const float* __restrict__ Wv, const float* __restrict__ Wp,
                 const float* __restrict__ W1, const float* __restrict__ W2,
                 u16* __restrict__ Wt)
{
    int id = blockIdx.x;
    const float* src; u16* dst; int Kd, Nd;
    if (id < 2304) {
        const int m = id / 576; id -= m * 576;
        src = (m == 0) ? Wq : (m == 1) ? Wk : (m == 2) ? Wv : Wp;
        dst = Wt + (size_t)m * 589824; Kd = 768; Nd = 768;
    } else if (id < 4608) {
        id -= 2304; src = W1; dst = Wt + (size_t)4 * 589824; Kd = 768; Nd = 3072;
    } else {
        id -= 4608; src = W2; dst = Wt + (size_t)4 * 589824 + 2359296; Kd = 3072; Nd = 768;
    }
    const int tn_n = Nd >> 5;
    const int tk = id / tn_n, tn = id - tk * tn_n;
    __shared__ float tile[32][33];
    const int tx = threadIdx.x & 31, ty = threadIdx.x >> 5;
    #pragma unroll
    for (int i = 0; i < 4; i++)
        tile[ty + i * 8][tx] = src[(size_t)(tk * 32 + ty + i * 8) * Nd + tn * 32 + tx];
    __syncthreads();
    #pragma unroll
    for (int i = 0; i < 4; i++)
        dst[(size_t)(tn * 32 + ty + i * 8) * Kd + tk * 32 + tx] = f2bf(tile[tx][ty + i * 8]);
}

__global__ void cvt_cond_k(const float* __restrict__ cond, u16* __restrict__ condb) {
    const int r = blockIdx.x, k = threadIdx.x;
    condb[(size_t)r * 448 + k] = (k < 438) ? f2bf(cond[(size_t)r * 438 + k]) : (u16)0;
}
__global__ void cvt_condw_k(const float* __restrict__ cw, u16* __restrict__ cwt) {
    const int n = blockIdx.x, k = threadIdx.x;
    cwt[(size_t)n * 448 + k] = (k < 438) ? f2bf(cw[(size_t)k * 768 + n]) : (u16)0;
}

// Token + positional embedding for segments 1,2 (rows 512..1535 per b).
__global__ void embed_k(const int* __restrict__ iu, const int* __restrict__ idn,
                        const float* __restrict__ eu, const float* __restrict__ ed,
                        const float* __restrict__ pos, float* __restrict__ x)
{
    const int t = blockIdx.x * 256 + threadIdx.x;  // 8*1024*192 float4s
    const int d4 = t % 192;
    const int row = t / 192;
    const int b = row >> 10, pl = row & 1023;
    const float* src; int posrow;
    if (pl < 512) { src = eu + (size_t)iu[b * 512 + pl] * 768; posrow = 512 + pl; }
    else { src = ed + (size_t)idn[b * 512 + pl - 512] * 768; posrow = 1024 + (pl - 512); }
    float4 v = ((const float4*)src)[d4];
    const float4 p = ((const float4*)(pos + (size_t)posrow * 768))[d4];
    v.x += p.x; v.y += p.y; v.z += p.z; v.w += p.w;
    ((float4*)(x + ((size_t)b * 1536 + posrow) * 768))[d4] = v;
}

extern "C" void kernel_launch(void* const* d_in, const int* in_sizes, int n_in,
                              void* d_out, int out_size, void* d_ws, size_t ws_size,
                              hipStream_t stream)
{
    const int*   idx_up   = (const int*)d_in[0];
    const int*   idx_down = (const int*)d_in[1];
    const float* cond     = (const float*)d_in[2];
    const float* emb_up   = (const float*)d_in[3];
    const float* emb_down = (const float*)d_in[4];
    const float* pos      = (const float*)d_in[5];
    const float* cond_w   = (const float*)d_in[6];
    const float* cond_b   = (const float*)d_in[7];
    const float* ln1_w    = (const float*)d_in[8];
    const float* ln1_b    = (const float*)d_in[9];
    const float* ln2_w    = (const float*)d_in[10];
    const float* ln2_b    = (const float*)d_in[11];
    const float* Wq = (const float*)d_in[12]; const float* bq = (const float*)d_in[13];
    const float* Wk = (const float*)d_in[14]; const float* bk = (const float*)d_in[15];
    const float* Wv = (const float*)d_in[16]; const float* bv = (const float*)d_in[17];
    const float* Wp = (const float*)d_in[18]; const float* bp = (const float*)d_in[19];
    const float* W1 = (const float*)d_in[20]; const float* b1 = (const float*)d_in[21];
    const float* W2 = (const float*)d_in[22]; const float* b2 = (const float*)d_in[23];

    float* x = (float*)d_out;  // residual stream lives in d_out (B,T,D) fp32

    u16* h     = (u16*)d_ws;           // 12288x768
    u16* qkv   = h + 9437184;          // 12288x2304
    u16* y     = qkv + 28311552;       // 12288x768
    u16* h1    = y + 9437184;          // 12288x3072
    u16* Wt    = h1 + 37748736;        // 7077888 (per-layer slot)
    u16* condb = Wt + 7077888;         // 4096x448
    u16* cwt   = condb + 1835008;      // 768x448

    cvt_cond_k<<<4096, 448, 0, stream>>>(cond, condb);
    cvt_condw_k<<<768, 448, 0, stream>>>(cond_w, cwt);
    embed_k<<<6144, 256, 0, stream>>>(idx_up, idx_down, emb_up, emb_down, pos, x);
    gemm_k<EP_COND><<<dim3(6, 32), 256, 0, stream>>>(condb, cwt, 4096, 768, 448,
        cond_b, nullptr, nullptr, x, nullptr, pos);

    for (int l = 0; l < 12; l++) {
        cvt_layer_k<<<6912, 256, 0, stream>>>(
            Wq + (size_t)l * 589824, Wk + (size_t)l * 589824, Wv + (size_t)l * 589824,
            Wp + (size_t)l * 589824, W1 + (size_t)l * 2359296, W2 + (size_t)l * 2359296, Wt);
        ln_k<<<3072, 256, 0, stream>>>(x, ln1_w + l * 768, ln1_b + l * 768, h);
        gemm_k<EP_QKV><<<dim3(18, 96), 256, 0, stream>>>(h, Wt, 12288, 2304, 768,
            bq + l * 768, bk + l * 768, bv + l * 768, nullptr, qkv, nullptr);
        attn_k<<<dim3(24, 12, 8), 256, 0, stream>>>(qkv, y);
        gemm_k<EP_RESID><<<dim3(6, 96), 256, 0, stream>>>(y, Wt + (size_t)3 * 589824,
            12288, 768, 768, bp + l * 768, nullptr, nullptr, x, nullptr, nullptr);
        ln_k<<<3072, 256, 0, stream>>>(x, ln2_w + l * 768, ln2_b + l * 768, h);
        gemm_k<EP_GELU><<<dim3(24, 96), 256, 0, stream>>>(h, Wt + (size_t)4 * 589824,
            12288, 3072, 768, b1 + l * 3072, nullptr, nullptr, nullptr, h1, nullptr);
        gemm_k<EP_RESID><<<dim3(6, 96), 256, 0, stream>>>(h1,
            Wt + (size_t)4 * 589824 + 2359296, 12288, 768, 3072,
            b2 + l * 768, nullptr, nullptr, x, nullptr, nullptr);
    }
}